// Round 1
// baseline (727.165 us; speedup 1.0000x reference)
//
#include <hip/hip_runtime.h>

#define N_NODES 50000
#define N_EDGES 600000
#define D 128
#define BN_EPS 1e-5f

// ---------------- degree count ----------------
__global__ void deg_kernel(const int* __restrict__ src, const int* __restrict__ dst,
                           float* __restrict__ deg_out, float* __restrict__ deg_in) {
    int i = blockIdx.x * blockDim.x + threadIdx.x;
    int stride = gridDim.x * blockDim.x;
    for (; i < N_EDGES; i += stride) {
        atomicAdd(&deg_out[src[i]], 1.0f);
        atomicAdd(&deg_in[dst[i]], 1.0f);
    }
}

// ---------------- edge scatter: agg[dst] += X[src] * rsqrt(max(deg_out[src],1)) ----------------
__global__ void scatter_kernel(const float* __restrict__ X, const int* __restrict__ src,
                               const int* __restrict__ dst, const float* __restrict__ deg_out,
                               float* __restrict__ agg) {
    // 128 threads per edge, 2 edges per 256-thread block iteration
    int d = threadIdx.x & 127;
    int slot = threadIdx.x >> 7;
    int e = blockIdx.x * 2 + slot;
    int estride = gridDim.x * 2;
    for (; e < N_EDGES; e += estride) {
        int s = src[e];
        int t = dst[e];
        float ns = rsqrtf(fmaxf(deg_out[s], 1.0f));
        atomicAdd(&agg[(size_t)t * D + d], X[(size_t)s * D + d] * ns);
    }
}

// ---------------- fused dual GEMM + ReLU + residual ----------------
// out[i][d] = relu( nd_i * sum_k agg[i][k]*W[k][d] ) + relu( sum_k X[i][k]*Wres[k][d] )
__global__ void gemm_kernel(const float* __restrict__ X, const float* __restrict__ agg,
                            const float* __restrict__ deg_in,
                            const float* __restrict__ W, const float* __restrict__ Wres,
                            float* __restrict__ out) {
    size_t idx = (size_t)blockIdx.x * blockDim.x + threadIdx.x;
    size_t total = (size_t)N_NODES * D;
    size_t stride = (size_t)gridDim.x * blockDim.x;
    for (; idx < total; idx += stride) {
        int i = (int)(idx >> 7);
        int dcol = (int)(idx & 127);
        float nd = rsqrtf(fmaxf(deg_in[i], 1.0f));
        const float* __restrict__ arow = agg + (size_t)i * D;
        const float* __restrict__ xrow = X + (size_t)i * D;
        float acc1 = 0.f, acc2 = 0.f;
#pragma unroll 8
        for (int k = 0; k < D; ++k) {
            acc1 = fmaf(arow[k], W[k * D + dcol], acc1);
            acc2 = fmaf(xrow[k], Wres[k * D + dcol], acc2);
        }
        out[idx] = fmaxf(acc1 * nd, 0.f) + fmaxf(acc2, 0.f);
    }
}

// ---------------- BatchNorm stats (column sums over nodes) ----------------
__global__ void bn_stats_kernel(const float* __restrict__ gX, float* __restrict__ sums,
                                float* __restrict__ sumsq) {
    int d = threadIdx.x & 127;
    int half = threadIdx.x >> 7;
    float s = 0.f, s2 = 0.f;
    for (int i = blockIdx.x * 2 + half; i < N_NODES; i += gridDim.x * 2) {
        float v = gX[(size_t)i * D + d];
        s += v;
        s2 += v * v;
    }
    __shared__ float ls[256];
    __shared__ float ls2[256];
    ls[threadIdx.x] = s;
    ls2[threadIdx.x] = s2;
    __syncthreads();
    if (threadIdx.x < 128) {
        s = ls[threadIdx.x] + ls[threadIdx.x + 128];
        s2 = ls2[threadIdx.x] + ls2[threadIdx.x + 128];
        atomicAdd(&sums[d], s);
        atomicAdd(&sumsq[d], s2);
    }
}

// ---------------- BatchNorm apply (in place on d_out) ----------------
__global__ void bn_apply_kernel(float* __restrict__ out, const float* __restrict__ sums,
                                const float* __restrict__ sumsq, const float* __restrict__ gamma,
                                const float* __restrict__ beta) {
    size_t idx = (size_t)blockIdx.x * blockDim.x + threadIdx.x;
    size_t total = (size_t)N_NODES * D;
    size_t stride = (size_t)gridDim.x * blockDim.x;
    const float invN = 1.0f / (float)N_NODES;
    for (; idx < total; idx += stride) {
        int d = (int)(idx & 127);
        float mean = sums[d] * invN;
        float var = sumsq[d] * invN - mean * mean;
        float inv = rsqrtf(var + BN_EPS);
        float v = out[idx];
        out[idx] = gamma[d] * (v - mean) * inv + beta[d];
    }
}

extern "C" void kernel_launch(void* const* d_in, const int* in_sizes, int n_in,
                              void* d_out, int out_size, void* d_ws, size_t ws_size,
                              hipStream_t stream) {
    const float* X = (const float*)d_in[0];
    const float* W = (const float*)d_in[1];
    const float* Wres = (const float*)d_in[2];
    const float* gamma = (const float*)d_in[3];
    const float* beta = (const float*)d_in[4];
    const int* src = (const int*)d_in[5];
    const int* dst = (const int*)d_in[6];
    float* out = (float*)d_out;

    // ws layout (floats): deg_out[50048] | deg_in[50048] | sums[128] | sumsq[128] | agg[N*D]
    float* ws = (float*)d_ws;
    float* deg_out = ws;
    float* deg_in = deg_out + 50048;
    float* sums = deg_in + 50048;
    float* sumsq = sums + 128;
    float* agg = sumsq + 128;
    size_t zero_bytes = (size_t)(50048 * 2 + 256 + (size_t)N_NODES * D) * sizeof(float);

    hipMemsetAsync(d_ws, 0, zero_bytes, stream);

    // degrees
    deg_kernel<<<2048, 256, 0, stream>>>(src, dst, deg_out, deg_in);

    // scatter-aggregate
    {
        int blocks = (N_EDGES + 1) / 2;  // 2 edges per block
        scatter_kernel<<<blocks, 256, 0, stream>>>(X, src, dst, deg_out, agg);
    }

    // fused dual GEMM + relu + residual -> d_out
    {
        size_t total = (size_t)N_NODES * D;
        int blocks = (int)((total + 255) / 256);
        gemm_kernel<<<blocks, 256, 0, stream>>>(X, agg, deg_in, W, Wres, out);
    }

    // batchnorm
    bn_stats_kernel<<<1024, 256, 0, stream>>>(out, sums, sumsq);
    {
        size_t total = (size_t)N_NODES * D;
        int blocks = (int)((total + 255) / 256);
        bn_apply_kernel<<<blocks, 256, 0, stream>>>(out, sums, sumsq, gamma, beta);
    }
}

// Round 3
// 350.115 us; speedup vs baseline: 2.0769x; 2.0769x over previous
//
#include <hip/hip_runtime.h>

#define N_NODES 50000
#define N_EDGES 600000
#define D 128
#define BN_EPS 1e-5f

// ws layout in 4-byte words:
#define OFF_CNT_OUT   0            // int[50048]
#define OFF_CNT_IN    50048        // int[50048]
#define OFF_CURSOR    100096       // int[50048]
#define OFF_SUMS      150144       // float[128]
#define OFF_SUMSQ     150272       // float[128]
#define ZERO_WORDS    150400       // everything above gets memset to 0
#define OFF_NS        150400       // float[50048]
#define OFF_ND        200448       // float[50048]
#define OFF_ROWSTART  250496       // int[50052]
#define OFF_CSR       300548       // int[600000]
#define OFF_AGG       900608       // bf16[50000*128] (as ushort), 8B-aligned base
// total bytes = 900608*4 + 12,800,000 = 16,402,432

static __device__ __forceinline__ unsigned short f2bf(float f) {
    unsigned u = __float_as_uint(f);
    unsigned r = (u + 0x7FFFu + ((u >> 16) & 1u)) >> 16;
    return (unsigned short)r;
}
static __device__ __forceinline__ float bf2f(unsigned short h) {
    return __uint_as_float(((unsigned)h) << 16);
}
static __device__ __forceinline__ void fma4(float4& acc, float s, const float4& wv) {
    acc.x = fmaf(s, wv.x, acc.x);
    acc.y = fmaf(s, wv.y, acc.y);
    acc.z = fmaf(s, wv.z, acc.z);
    acc.w = fmaf(s, wv.w, acc.w);
}

// ---------------- degree count (int) ----------------
__global__ void deg_kernel(const int* __restrict__ src, const int* __restrict__ dst,
                           int* __restrict__ cnt_out, int* __restrict__ cnt_in) {
    int i = blockIdx.x * blockDim.x + threadIdx.x;
    if (i < N_EDGES) {
        atomicAdd(&cnt_out[src[i]], 1);
        atomicAdd(&cnt_in[dst[i]], 1);
    }
}

// ---------------- norm factors ----------------
__global__ void norm_kernel(const int* __restrict__ cnt_out, const int* __restrict__ cnt_in,
                            float* __restrict__ ns, float* __restrict__ nd) {
    int i = blockIdx.x * blockDim.x + threadIdx.x;
    if (i < N_NODES) {
        ns[i] = rsqrtf((float)max(cnt_out[i], 1));
        nd[i] = rsqrtf((float)max(cnt_in[i], 1));
    }
}

// ---------------- exclusive prefix scan of cnt_in -> row_start (single block, 1024 thr) ----------------
__global__ void scan_kernel(const int* __restrict__ cnt, int* __restrict__ row_start) {
    __shared__ int wsum[16];
    __shared__ int carry_s;
    int tid = threadIdx.x;
    int lane = tid & 63;
    int wid = tid >> 6;
    if (tid == 0) carry_s = 0;
    __syncthreads();
    for (int base = 0; base < N_NODES; base += 1024) {
        int idx = base + tid;
        int v = (idx < N_NODES) ? cnt[idx] : 0;
        // inclusive scan within wave
        int s = v;
        #pragma unroll
        for (int off = 1; off < 64; off <<= 1) {
            int u = __shfl_up(s, off);
            if (lane >= off) s += u;
        }
        if (lane == 63) wsum[wid] = s;
        __syncthreads();
        if (wid == 0) {
            int ws = (lane < 16) ? wsum[lane] : 0;
            #pragma unroll
            for (int off = 1; off < 16; off <<= 1) {
                int u = __shfl_up(ws, off);
                if (lane >= off) ws += u;
            }
            if (lane < 16) wsum[lane] = ws;
        }
        __syncthreads();
        int woff = (wid > 0) ? wsum[wid - 1] : 0;
        if (idx < N_NODES) row_start[idx] = carry_s + woff + s - v;
        __syncthreads();
        if (tid == 0) carry_s += wsum[15];
        __syncthreads();
    }
    if (tid == 0) row_start[N_NODES] = carry_s;
}

// ---------------- CSR fill ----------------
__global__ void fill_kernel(const int* __restrict__ src, const int* __restrict__ dst,
                            const int* __restrict__ row_start, int* __restrict__ cursor,
                            int* __restrict__ csr) {
    int e = blockIdx.x * blockDim.x + threadIdx.x;
    if (e < N_EDGES) {
        int t = dst[e];
        int p = atomicAdd(&cursor[t], 1);
        csr[row_start[t] + p] = src[e];
    }
}

// ---------------- gather aggregate: one wave per node ----------------
__global__ void gather_kernel(const float* __restrict__ X, const int* __restrict__ csr,
                              const int* __restrict__ row_start, const float* __restrict__ ns,
                              const float* __restrict__ nd, unsigned short* __restrict__ aggb) {
    int lane = threadIdx.x & 63;
    int wid = threadIdx.x >> 6;
    int node = blockIdx.x * 4 + wid;
    if (node >= N_NODES) return;
    int beg = row_start[node];
    int end = row_start[node + 1];
    const float2* __restrict__ X2 = (const float2*)X;
    float ax = 0.f, ay = 0.f;
    for (int e = beg; e < end; ++e) {
        int s = csr[e];
        float w = ns[s];
        float2 xv = X2[(size_t)s * 64 + lane];
        ax = fmaf(xv.x, w, ax);
        ay = fmaf(xv.y, w, ay);
    }
    float ndv = nd[node];
    ax *= ndv;
    ay *= ndv;
    ushort2 o;
    o.x = f2bf(ax);
    o.y = f2bf(ay);
    *(ushort2*)(aggb + (size_t)node * D + lane * 2) = o;
}

// ---------------- LDS-tiled fused dual GEMM + relu + residual ----------------
// Block: 256 threads, BM=64 rows x BN=128 cols. K-tiles of 32.
__global__ __launch_bounds__(256) void gemm_kernel(
    const float* __restrict__ X, const unsigned short* __restrict__ aggb,
    const float* __restrict__ W, const float* __restrict__ Wres,
    float* __restrict__ out) {
    __shared__ float Wlds[32 * 128];
    __shared__ float Wrlds[32 * 128];
    __shared__ float Alds[64 * 32];
    __shared__ float Xlds[64 * 32];
    int t = threadIdx.x;
    int row0 = blockIdx.x * 64;
    int tcol = t & 31;   // col group: cols 4*tcol .. 4*tcol+3
    int trow = t >> 5;   // row group: rows 8*trow .. 8*trow+7
    int r0 = trow * 8;
    int c0 = tcol * 4;
    float4 acc1[8];
    float4 acc2[8];
    #pragma unroll
    for (int i = 0; i < 8; ++i) {
        acc1[i] = make_float4(0.f, 0.f, 0.f, 0.f);
        acc2[i] = make_float4(0.f, 0.f, 0.f, 0.f);
    }
    for (int kt = 0; kt < 4; ++kt) {
        int k0 = kt * 32;
        __syncthreads();
        // stage W, Wres: 1024 float4 each; fi -> (krow = fi>>5, c4 = fi&31)
        #pragma unroll
        for (int j = 0; j < 4; ++j) {
            int fi = t + j * 256;
            int kr = fi >> 5, c4 = fi & 31;
            ((float4*)Wlds)[fi] = *(const float4*)(W + (size_t)(k0 + kr) * 128 + c4 * 4);
            ((float4*)Wrlds)[fi] = *(const float4*)(Wres + (size_t)(k0 + kr) * 128 + c4 * 4);
        }
        // stage A (bf16 -> f32) and X: 512 x (4 elems) each; fi -> (r = fi>>3, q = fi&7)
        #pragma unroll
        for (int j = 0; j < 2; ++j) {
            int fi = t + j * 256;
            int r = fi >> 3, q = fi & 7;
            int grow = row0 + r;
            float4 av = make_float4(0.f, 0.f, 0.f, 0.f);
            float4 xv = make_float4(0.f, 0.f, 0.f, 0.f);
            if (grow < N_NODES) {
                ushort4 u = *(const ushort4*)(aggb + (size_t)grow * 128 + k0 + q * 4);
                av.x = bf2f(u.x);
                av.y = bf2f(u.y);
                av.z = bf2f(u.z);
                av.w = bf2f(u.w);
                xv = *(const float4*)(X + (size_t)grow * 128 + k0 + q * 4);
            }
            ((float4*)Alds)[r * 8 + q] = av;
            ((float4*)Xlds)[r * 8 + q] = xv;
        }
        __syncthreads();
        // compute: 8 quads of k (4 k's each)
        #pragma unroll
        for (int q = 0; q < 8; ++q) {
            float4 w0 = ((float4*)Wlds)[(q * 4 + 0) * 32 + tcol];
            float4 w1 = ((float4*)Wlds)[(q * 4 + 1) * 32 + tcol];
            float4 w2 = ((float4*)Wlds)[(q * 4 + 2) * 32 + tcol];
            float4 w3 = ((float4*)Wlds)[(q * 4 + 3) * 32 + tcol];
            float4 u0 = ((float4*)Wrlds)[(q * 4 + 0) * 32 + tcol];
            float4 u1 = ((float4*)Wrlds)[(q * 4 + 1) * 32 + tcol];
            float4 u2 = ((float4*)Wrlds)[(q * 4 + 2) * 32 + tcol];
            float4 u3 = ((float4*)Wrlds)[(q * 4 + 3) * 32 + tcol];
            #pragma unroll
            for (int i = 0; i < 8; ++i) {
                float4 a = ((float4*)Alds)[(r0 + i) * 8 + q];
                float4 x = ((float4*)Xlds)[(r0 + i) * 8 + q];
                fma4(acc1[i], a.x, w0);
                fma4(acc1[i], a.y, w1);
                fma4(acc1[i], a.z, w2);
                fma4(acc1[i], a.w, w3);
                fma4(acc2[i], x.x, u0);
                fma4(acc2[i], x.y, u1);
                fma4(acc2[i], x.z, u2);
                fma4(acc2[i], x.w, u3);
            }
        }
    }
    // epilogue: relu + relu-residual  (norm_dst already folded into agg)
    #pragma unroll
    for (int i = 0; i < 8; ++i) {
        int grow = row0 + r0 + i;
        if (grow < N_NODES) {
            float4 o;
            o.x = fmaxf(acc1[i].x, 0.f) + fmaxf(acc2[i].x, 0.f);
            o.y = fmaxf(acc1[i].y, 0.f) + fmaxf(acc2[i].y, 0.f);
            o.z = fmaxf(acc1[i].z, 0.f) + fmaxf(acc2[i].z, 0.f);
            o.w = fmaxf(acc1[i].w, 0.f) + fmaxf(acc2[i].w, 0.f);
            *(float4*)(out + (size_t)grow * 128 + c0) = o;
        }
    }
}

// ---------------- BatchNorm stats ----------------
__global__ void bn_stats_kernel(const float* __restrict__ gX, float* __restrict__ sums,
                                float* __restrict__ sumsq) {
    int d = threadIdx.x & 127;
    int half = threadIdx.x >> 7;
    float s = 0.f, s2 = 0.f;
    for (int i = blockIdx.x * 2 + half; i < N_NODES; i += gridDim.x * 2) {
        float v = gX[(size_t)i * D + d];
        s += v;
        s2 += v * v;
    }
    __shared__ float ls[256];
    __shared__ float ls2[256];
    ls[threadIdx.x] = s;
    ls2[threadIdx.x] = s2;
    __syncthreads();
    if (threadIdx.x < 128) {
        s = ls[threadIdx.x] + ls[threadIdx.x + 128];
        s2 = ls2[threadIdx.x] + ls2[threadIdx.x + 128];
        atomicAdd(&sums[d], s);
        atomicAdd(&sumsq[d], s2);
    }
}

// ---------------- BatchNorm apply (in place) ----------------
__global__ void bn_apply_kernel(float* __restrict__ out, const float* __restrict__ sums,
                                const float* __restrict__ sumsq, const float* __restrict__ gamma,
                                const float* __restrict__ beta) {
    size_t idx = (size_t)blockIdx.x * blockDim.x + threadIdx.x;
    size_t total = (size_t)N_NODES * D;
    if (idx >= total) return;
    int d = (int)(idx & 127);
    const float invN = 1.0f / (float)N_NODES;
    float mean = sums[d] * invN;
    float var = sumsq[d] * invN - mean * mean;
    float inv = rsqrtf(var + BN_EPS);
    float v = out[idx];
    out[idx] = gamma[d] * (v - mean) * inv + beta[d];
}

extern "C" void kernel_launch(void* const* d_in, const int* in_sizes, int n_in,
                              void* d_out, int out_size, void* d_ws, size_t ws_size,
                              hipStream_t stream) {
    const float* X = (const float*)d_in[0];
    const float* W = (const float*)d_in[1];
    const float* Wres = (const float*)d_in[2];
    const float* gamma = (const float*)d_in[3];
    const float* beta = (const float*)d_in[4];
    const int* src = (const int*)d_in[5];
    const int* dst = (const int*)d_in[6];
    float* out = (float*)d_out;

    int* wsI = (int*)d_ws;
    int* cnt_out = wsI + OFF_CNT_OUT;
    int* cnt_in = wsI + OFF_CNT_IN;
    int* cursor = wsI + OFF_CURSOR;
    float* sums = (float*)(wsI + OFF_SUMS);
    float* sumsq = (float*)(wsI + OFF_SUMSQ);
    float* ns = (float*)(wsI + OFF_NS);
    float* nd = (float*)(wsI + OFF_ND);
    int* row_start = wsI + OFF_ROWSTART;
    int* csr = wsI + OFF_CSR;
    unsigned short* aggb = (unsigned short*)(wsI + OFF_AGG);

    hipMemsetAsync(d_ws, 0, (size_t)ZERO_WORDS * 4, stream);

    deg_kernel<<<(N_EDGES + 255) / 256, 256, 0, stream>>>(src, dst, cnt_out, cnt_in);
    norm_kernel<<<(N_NODES + 255) / 256, 256, 0, stream>>>(cnt_out, cnt_in, ns, nd);
    scan_kernel<<<1, 1024, 0, stream>>>(cnt_in, row_start);
    fill_kernel<<<(N_EDGES + 255) / 256, 256, 0, stream>>>(src, dst, row_start, cursor, csr);
    gather_kernel<<<(N_NODES + 3) / 4, 256, 0, stream>>>(X, csr, row_start, ns, nd, aggb);
    gemm_kernel<<<(N_NODES + 63) / 64, 256, 0, stream>>>(X, aggb, W, Wres, out);
    bn_stats_kernel<<<1024, 256, 0, stream>>>(out, sums, sumsq);
    bn_apply_kernel<<<(N_NODES * D + 255) / 256, 256, 0, stream>>>(out, sums, sumsq, gamma, beta);
}

// Round 4
// 267.246 us; speedup vs baseline: 2.7210x; 1.3101x over previous
//
#include <hip/hip_runtime.h>

#define N_NODES 50000
#define N_EDGES 600000
#define D 128
#define BN_EPS 1e-5f

// ws layout in 4-byte words:
#define OFF_CNT_OUT   0            // int[50048]
#define OFF_CNT_IN    50048        // int[50048]
#define OFF_SUMS      100096       // float[128]
#define OFF_SUMSQ     100224       // float[128]
#define ZERO_WORDS    100352       // everything above is memset to 0 each call
#define OFF_NS        100352       // float[50048]
#define OFF_ND        150400       // float[50048]
#define OFF_ROWSTART  200448       // int[50052]
#define OFF_CURSOR    250500       // int[50048]
#define OFF_CSR       300548       // int[600000]
#define OFF_WPK       900548       // bf16[128*128] packed B-frags (16B-aligned)
#define OFF_WRPK      908740       // bf16[128*128] packed B-frags
#define OFF_XB        916932       // bf16[50000*128] row-major
// total = 4,116,932 words = 16.47 MB (R3 used 16.4 MB successfully)

typedef __attribute__((ext_vector_type(8))) __bf16 bf16x8;
typedef __attribute__((ext_vector_type(4))) float f32x4;

static __device__ __forceinline__ unsigned short f2bf(float f) {
    unsigned u = __float_as_uint(f);
    unsigned r = (u + 0x7FFFu + ((u >> 16) & 1u)) >> 16;
    return (unsigned short)r;
}
static __device__ __forceinline__ float bf2f(unsigned short h) {
    return __uint_as_float(((unsigned)h) << 16);
}

// ---------------- X -> bf16 ----------------
__global__ void cvtX_kernel(const float* __restrict__ X, unsigned short* __restrict__ Xb) {
    int tid = blockIdx.x * 256 + threadIdx.x;  // one per 8 elems
    if (tid >= N_NODES * D / 8) return;
    const float4* X4 = (const float4*)X;
    float4 a = X4[tid * 2];
    float4 b = X4[tid * 2 + 1];
    union { unsigned short us[8]; uint4 v; } u;
    u.us[0] = f2bf(a.x); u.us[1] = f2bf(a.y); u.us[2] = f2bf(a.z); u.us[3] = f2bf(a.w);
    u.us[4] = f2bf(b.x); u.us[5] = f2bf(b.y); u.us[6] = f2bf(b.z); u.us[7] = f2bf(b.w);
    ((uint4*)Xb)[tid] = u.v;
}

// ---------------- pack W, Wres into 16x16x32 B-fragment order ----------------
// frag (c=coltile 0..7, t=ktile 0..3): lane l holds B[t*32 + (l>>4)*8 + j][c*16 + (l&15)]
// flat frag index = (c*4 + t)*64 + l  == tid
__global__ void packW_kernel(const float* __restrict__ W, const float* __restrict__ Wres,
                             unsigned short* __restrict__ Wpk, unsigned short* __restrict__ Wrpk) {
    int tid = blockIdx.x * 256 + threadIdx.x;  // 0..2047
    if (tid >= 2048) return;
    int l = tid & 63;
    int t = (tid >> 6) & 3;
    int c = tid >> 8;
    int col = c * 16 + (l & 15);
    int k0 = t * 32 + (l >> 4) * 8;
    union { unsigned short us[8]; uint4 v; } u1, u2;
    #pragma unroll
    for (int j = 0; j < 8; ++j) {
        u1.us[j] = f2bf(W[(size_t)(k0 + j) * 128 + col]);
        u2.us[j] = f2bf(Wres[(size_t)(k0 + j) * 128 + col]);
    }
    ((uint4*)Wpk)[tid] = u1.v;
    ((uint4*)Wrpk)[tid] = u2.v;
}

// ---------------- degree count ----------------
__global__ void deg_kernel(const int* __restrict__ src, const int* __restrict__ dst,
                           int* __restrict__ cnt_out, int* __restrict__ cnt_in) {
    int i = blockIdx.x * blockDim.x + threadIdx.x;
    if (i < N_EDGES) {
        atomicAdd(&cnt_out[src[i]], 1);
        atomicAdd(&cnt_in[dst[i]], 1);
    }
}

// ---------------- norm factors ----------------
__global__ void norm_kernel(const int* __restrict__ cnt_out, const int* __restrict__ cnt_in,
                            float* __restrict__ ns, float* __restrict__ nd) {
    int i = blockIdx.x * blockDim.x + threadIdx.x;
    if (i < N_NODES) {
        ns[i] = rsqrtf((float)max(cnt_out[i], 1));
        nd[i] = rsqrtf((float)max(cnt_in[i], 1));
    }
}

// ---------------- exclusive scan of cnt_in -> row_start (+ cursor copy) ----------------
__global__ void scan_kernel(const int* __restrict__ cnt, int* __restrict__ row_start,
                            int* __restrict__ cursor) {
    __shared__ int wsum[16];
    __shared__ int carry_s;
    int tid = threadIdx.x;
    int lane = tid & 63;
    int wid = tid >> 6;
    if (tid == 0) carry_s = 0;
    __syncthreads();
    for (int base = 0; base < N_NODES; base += 1024) {
        int idx = base + tid;
        int v = (idx < N_NODES) ? cnt[idx] : 0;
        int s = v;
        #pragma unroll
        for (int off = 1; off < 64; off <<= 1) {
            int u = __shfl_up(s, off);
            if (lane >= off) s += u;
        }
        if (lane == 63) wsum[wid] = s;
        __syncthreads();
        if (wid == 0) {
            int ws = (lane < 16) ? wsum[lane] : 0;
            #pragma unroll
            for (int off = 1; off < 16; off <<= 1) {
                int u = __shfl_up(ws, off);
                if (lane >= off) ws += u;
            }
            if (lane < 16) wsum[lane] = ws;
        }
        __syncthreads();
        int woff = (wid > 0) ? wsum[wid - 1] : 0;
        if (idx < N_NODES) {
            int rs = carry_s + woff + s - v;
            row_start[idx] = rs;
            cursor[idx] = rs;
        }
        __syncthreads();
        if (tid == 0) carry_s += wsum[15];
        __syncthreads();
    }
    if (tid == 0) row_start[N_NODES] = carry_s;
}

// ---------------- CSR fill (absolute cursor) ----------------
__global__ void fill_kernel(const int* __restrict__ src, const int* __restrict__ dst,
                            int* __restrict__ cursor, int* __restrict__ csr) {
    int e = blockIdx.x * blockDim.x + threadIdx.x;
    if (e < N_EDGES) {
        int p = atomicAdd(&cursor[dst[e]], 1);
        csr[p] = src[e];
    }
}

// ---------------- fused gather + dual MFMA GEMM + relu/residual + BN stats ----------------
// 256 threads = 4 waves; wave w owns rowtile rt = blockIdx*4+w (16 node rows).
// Phase 1: wave gathers its 16 rows into wave-private padded LDS (row stride 272B).
// Phase 2: 16x16x32 bf16 MFMA against packed W frags, 8 coltiles, dual gemm.
__global__ __launch_bounds__(256) void fused_kernel(
    const unsigned short* __restrict__ Xb,
    const int* __restrict__ csr, const int* __restrict__ row_start,
    const float* __restrict__ ns, const float* __restrict__ nd,
    const unsigned short* __restrict__ Wpk, const unsigned short* __restrict__ Wrpk,
    float* __restrict__ out, float* __restrict__ sums, float* __restrict__ sumsq) {
    __shared__ unsigned short Alds[4][16 * 136];  // 136 ushorts = 272B row stride (pad kills bank conflict)
    __shared__ float lsum[128];
    __shared__ float lsq[128];
    int t = threadIdx.x;
    int w = t >> 6;
    int l = t & 63;
    if (t < 128) { lsum[t] = 0.f; lsq[t] = 0.f; }
    __syncthreads();
    int rt = blockIdx.x * 4 + w;

    // ---- gather phase (wave-private) ----
    for (int r = 0; r < 16; ++r) {
        int node = rt * 16 + r;
        float ax = 0.f, ay = 0.f;
        if (node < N_NODES) {
            int beg = row_start[node];
            int end = row_start[node + 1];
            int e = beg;
            for (; e + 1 < end; e += 2) {
                int s0 = csr[e];
                int s1 = csr[e + 1];
                float w0 = ns[s0];
                float w1 = ns[s1];
                ushort2 x0 = *(const ushort2*)(Xb + (size_t)s0 * 128 + l * 2);
                ushort2 x1 = *(const ushort2*)(Xb + (size_t)s1 * 128 + l * 2);
                ax = fmaf(bf2f(x0.x), w0, ax);
                ay = fmaf(bf2f(x0.y), w0, ay);
                ax = fmaf(bf2f(x1.x), w1, ax);
                ay = fmaf(bf2f(x1.y), w1, ay);
            }
            if (e < end) {
                int s0 = csr[e];
                float w0 = ns[s0];
                ushort2 x0 = *(const ushort2*)(Xb + (size_t)s0 * 128 + l * 2);
                ax = fmaf(bf2f(x0.x), w0, ax);
                ay = fmaf(bf2f(x0.y), w0, ay);
            }
            float ndv = nd[node];
            ax *= ndv;
            ay *= ndv;
        }
        ushort2 o;
        o.x = f2bf(ax);
        o.y = f2bf(ay);
        *(ushort2*)(&Alds[w][r * 136 + l * 2]) = o;
    }

    // ---- fragment loads ----
    int kg = l >> 4;
    int arow = rt * 16 + (l & 15);
    int srow = arow < N_NODES ? arow : N_NODES - 1;
    bf16x8 a1[4], a2[4];
    #pragma unroll
    for (int kt = 0; kt < 4; ++kt) {
        a1[kt] = *(const bf16x8*)(&Alds[w][(l & 15) * 136 + kt * 32 + kg * 8]);
        a2[kt] = *(const bf16x8*)(Xb + (size_t)srow * 128 + kt * 32 + kg * 8);
    }
    const bf16x8* BW = (const bf16x8*)Wpk;
    const bf16x8* BR = (const bf16x8*)Wrpk;

    // ---- MFMA + epilogue per coltile ----
    #pragma unroll
    for (int c = 0; c < 8; ++c) {
        f32x4 acc1 = {0.f, 0.f, 0.f, 0.f};
        f32x4 acc2 = {0.f, 0.f, 0.f, 0.f};
        #pragma unroll
        for (int kt = 0; kt < 4; ++kt)
            acc1 = __builtin_amdgcn_mfma_f32_16x16x32_bf16(a1[kt], BW[(c * 4 + kt) * 64 + l], acc1, 0, 0, 0);
        #pragma unroll
        for (int kt = 0; kt < 4; ++kt)
            acc2 = __builtin_amdgcn_mfma_f32_16x16x32_bf16(a2[kt], BR[(c * 4 + kt) * 64 + l], acc2, 0, 0, 0);
        int col = c * 16 + (l & 15);
        float s = 0.f, s2 = 0.f;
        #pragma unroll
        for (int i = 0; i < 4; ++i) {
            int crow = rt * 16 + kg * 4 + i;  // C/D layout: col=lane&15, row=(lane>>4)*4+i
            if (crow < N_NODES) {
                float v = fmaxf(acc1[i], 0.f) + fmaxf(acc2[i], 0.f);
                out[(size_t)crow * 128 + col] = v;
                s += v;
                s2 += v * v;
            }
        }
        s += __shfl_xor(s, 16);
        s2 += __shfl_xor(s2, 16);
        s += __shfl_xor(s, 32);
        s2 += __shfl_xor(s2, 32);
        if (l < 16) {
            atomicAdd(&lsum[col], s);
            atomicAdd(&lsq[col], s2);
        }
    }
    __syncthreads();
    if (t < 128) {
        atomicAdd(&sums[t], lsum[t]);
        atomicAdd(&sumsq[t], lsq[t]);
    }
}

// ---------------- BatchNorm apply (in place, float4) ----------------
__global__ void bn_apply_kernel(float* __restrict__ out, const float* __restrict__ sums,
                                const float* __restrict__ sumsq, const float* __restrict__ gamma,
                                const float* __restrict__ beta) {
    int tid = blockIdx.x * 256 + threadIdx.x;
    if (tid >= N_NODES * D / 4) return;
    int d0 = (tid * 4) & 127;
    const float invN = 1.0f / (float)N_NODES;
    float4 v = ((float4*)out)[tid];
    float m0 = sums[d0] * invN, m1 = sums[d0 + 1] * invN, m2 = sums[d0 + 2] * invN, m3 = sums[d0 + 3] * invN;
    float i0 = rsqrtf(sumsq[d0] * invN - m0 * m0 + BN_EPS);
    float i1 = rsqrtf(sumsq[d0 + 1] * invN - m1 * m1 + BN_EPS);
    float i2 = rsqrtf(sumsq[d0 + 2] * invN - m2 * m2 + BN_EPS);
    float i3 = rsqrtf(sumsq[d0 + 3] * invN - m3 * m3 + BN_EPS);
    v.x = gamma[d0] * (v.x - m0) * i0 + beta[d0];
    v.y = gamma[d0 + 1] * (v.y - m1) * i1 + beta[d0 + 1];
    v.z = gamma[d0 + 2] * (v.z - m2) * i2 + beta[d0 + 2];
    v.w = gamma[d0 + 3] * (v.w - m3) * i3 + beta[d0 + 3];
    ((float4*)out)[tid] = v;
}

extern "C" void kernel_launch(void* const* d_in, const int* in_sizes, int n_in,
                              void* d_out, int out_size, void* d_ws, size_t ws_size,
                              hipStream_t stream) {
    const float* X = (const float*)d_in[0];
    const float* W = (const float*)d_in[1];
    const float* Wres = (const float*)d_in[2];
    const float* gamma = (const float*)d_in[3];
    const float* beta = (const float*)d_in[4];
    const int* src = (const int*)d_in[5];
    const int* dst = (const int*)d_in[6];
    float* out = (float*)d_out;

    int* wsI = (int*)d_ws;
    int* cnt_out = wsI + OFF_CNT_OUT;
    int* cnt_in = wsI + OFF_CNT_IN;
    float* sums = (float*)(wsI + OFF_SUMS);
    float* sumsq = (float*)(wsI + OFF_SUMSQ);
    float* ns = (float*)(wsI + OFF_NS);
    float* nd = (float*)(wsI + OFF_ND);
    int* row_start = wsI + OFF_ROWSTART;
    int* cursor = wsI + OFF_CURSOR;
    int* csr = wsI + OFF_CSR;
    unsigned short* Wpk = (unsigned short*)(wsI + OFF_WPK);
    unsigned short* Wrpk = (unsigned short*)(wsI + OFF_WRPK);
    unsigned short* Xb = (unsigned short*)(wsI + OFF_XB);

    hipMemsetAsync(d_ws, 0, (size_t)ZERO_WORDS * 4, stream);

    cvtX_kernel<<<(N_NODES * D / 8 + 255) / 256, 256, 0, stream>>>(X, Xb);
    packW_kernel<<<8, 256, 0, stream>>>(W, Wres, Wpk, Wrpk);
    deg_kernel<<<(N_EDGES + 255) / 256, 256, 0, stream>>>(src, dst, cnt_out, cnt_in);
    norm_kernel<<<(N_NODES + 255) / 256, 256, 0, stream>>>(cnt_out, cnt_in, ns, nd);
    scan_kernel<<<1, 1024, 0, stream>>>(cnt_in, row_start, cursor);
    fill_kernel<<<(N_EDGES + 255) / 256, 256, 0, stream>>>(src, dst, cursor, csr);
    fused_kernel<<<(N_NODES + 63) / 64, 256, 0, stream>>>(Xb, csr, row_start, ns, nd, Wpk, Wrpk,
                                                          out, sums, sumsq);
    bn_apply_kernel<<<(N_NODES * D / 4 + 255) / 256, 256, 0, stream>>>(out, sums, sumsq, gamma, beta);
}

// Round 6
// 207.210 us; speedup vs baseline: 3.5093x; 1.2897x over previous
//
#include <hip/hip_runtime.h>

#define N_NODES 50000
#define N_EDGES 600000
#define D 128
#define BN_EPS 1e-5f
#define NBLK_SCAN 196   // ceil(50000/256)

// ws layout in 4-byte words:
#define OFF_CNT_OUT   0            // int[50048]
#define OFF_CNT_IN    50048        // int[50048]
#define OFF_SUMS      100096       // float[128]
#define OFF_SUMSQ     100224       // float[128]
#define ZERO_WORDS    100352       // memset range each call
#define OFF_PART      100352       // int[256]  (scanA partials; fully overwritten)
#define OFF_PART2     100608       // int[256]  (exclusive offsets)
#define OFF_NS        100864       // float[50048]
#define OFF_ND        150912       // float[50048]
#define OFF_ROWSTART  200960       // int[50052]
#define OFF_CURSOR    251012       // int[50048]
#define OFF_CSR       301060       // int[600000]
#define OFF_WPK       901060       // bf16[128*128] packed B-frags (16B aligned)
#define OFF_WRPK      909252       // bf16[128*128]
#define OFF_XS        917444       // bf16[50000*128] = X * norm_src, row-major (16B aligned)
// total = 4,117,444 words = 16.47 MB (R3/R4 proved >=16.47MB works)

typedef __attribute__((ext_vector_type(8))) __bf16 bf16x8;
typedef __attribute__((ext_vector_type(4))) float f32x4;

static __device__ __forceinline__ unsigned short f2bf(float f) {
    unsigned u = __float_as_uint(f);
    unsigned r = (u + 0x7FFFu + ((u >> 16) & 1u)) >> 16;
    return (unsigned short)r;
}
static __device__ __forceinline__ float bf2f(unsigned short h) {
    return __uint_as_float(((unsigned)h) << 16);
}

// ---------------- degrees + fused W packing ----------------
// packW: frag (c=coltile 0..7, t=ktile 0..3): lane l holds B[t*32+(l>>4)*8+j][c*16+(l&15)]
__global__ void deg_pack_kernel(const int* __restrict__ src, const int* __restrict__ dst,
                                int* __restrict__ cnt_out, int* __restrict__ cnt_in,
                                const float* __restrict__ W, const float* __restrict__ Wres,
                                unsigned short* __restrict__ Wpk, unsigned short* __restrict__ Wrpk) {
    int i = blockIdx.x * 256 + threadIdx.x;
    if (i < 2048) {
        int l = i & 63;
        int t = (i >> 6) & 3;
        int c = i >> 8;
        int col = c * 16 + (l & 15);
        int k0 = t * 32 + (l >> 4) * 8;
        union { unsigned short us[8]; uint4 v; } u1, u2;
        #pragma unroll
        for (int j = 0; j < 8; ++j) {
            u1.us[j] = f2bf(W[(size_t)(k0 + j) * 128 + col]);
            u2.us[j] = f2bf(Wres[(size_t)(k0 + j) * 128 + col]);
        }
        ((uint4*)Wpk)[i] = u1.v;
        ((uint4*)Wrpk)[i] = u2.v;
    }
    if (i < N_EDGES) {
        atomicAdd(&cnt_out[src[i]], 1);
        atomicAdd(&cnt_in[dst[i]], 1);
    }
}

// ---------------- norm factors + scan level A (block sums of cnt_in) ----------------
__global__ void norm_scanA_kernel(const int* __restrict__ cnt_out, const int* __restrict__ cnt_in,
                                  float* __restrict__ ns, float* __restrict__ nd,
                                  int* __restrict__ part) {
    int i = blockIdx.x * 256 + threadIdx.x;
    int v = 0;
    if (i < N_NODES) {
        int co = cnt_out[i];
        int ci = cnt_in[i];
        ns[i] = rsqrtf((float)max(co, 1));
        nd[i] = rsqrtf((float)max(ci, 1));
        v = ci;
    }
    int lane = threadIdx.x & 63;
    int wid = threadIdx.x >> 6;
    #pragma unroll
    for (int off = 32; off >= 1; off >>= 1) v += __shfl_xor(v, off);
    __shared__ int wsum[4];
    if (lane == 0) wsum[wid] = v;
    __syncthreads();
    if (threadIdx.x == 0) part[blockIdx.x] = wsum[0] + wsum[1] + wsum[2] + wsum[3];
}

// ---------------- scan level B: exclusive scan of NBLK_SCAN partials (1 block) ----------------
__global__ void scanB_kernel(const int* __restrict__ part, int* __restrict__ part2) {
    int tid = threadIdx.x;
    int v = (tid < NBLK_SCAN) ? part[tid] : 0;
    int lane = tid & 63;
    int wid = tid >> 6;
    int s = v;
    #pragma unroll
    for (int off = 1; off < 64; off <<= 1) {
        int u = __shfl_up(s, off);
        if (lane >= off) s += u;
    }
    __shared__ int wsum[4];
    if (lane == 63) wsum[wid] = s;
    __syncthreads();
    int add = 0;
    for (int k = 0; k < wid; ++k) add += wsum[k];
    if (tid < NBLK_SCAN) part2[tid] = add + s - v;
}

// ---------------- scan level C: per-block exclusive scan + offset -> row_start, cursor ----------------
__global__ void scanC_kernel(const int* __restrict__ cnt_in, const int* __restrict__ part2,
                             int* __restrict__ row_start, int* __restrict__ cursor) {
    int i = blockIdx.x * 256 + threadIdx.x;
    int v = (i < N_NODES) ? cnt_in[i] : 0;
    int lane = threadIdx.x & 63;
    int wid = threadIdx.x >> 6;
    int s = v;
    #pragma unroll
    for (int off = 1; off < 64; off <<= 1) {
        int u = __shfl_up(s, off);
        if (lane >= off) s += u;
    }
    __shared__ int wsum[4];
    if (lane == 63) wsum[wid] = s;
    __syncthreads();
    int add = part2[blockIdx.x];
    for (int k = 0; k < wid; ++k) add += wsum[k];
    if (i < N_NODES) {
        int rs = add + s - v;
        row_start[i] = rs;
        cursor[i] = rs;
    }
    if (i == N_NODES) row_start[N_NODES] = N_EDGES;
}

// ---------------- X * norm_src -> bf16 Xs ----------------
__global__ void cvtXs_kernel(const float* __restrict__ X, const float* __restrict__ ns,
                             unsigned short* __restrict__ Xs) {
    int tid = blockIdx.x * 256 + threadIdx.x;  // one per 8 elems
    if (tid >= N_NODES * D / 8) return;
    int row = tid >> 4;
    float w = ns[row];
    const float4* X4 = (const float4*)X;
    float4 a = X4[tid * 2];
    float4 b = X4[tid * 2 + 1];
    union { unsigned short us[8]; uint4 v; } u;
    u.us[0] = f2bf(a.x * w); u.us[1] = f2bf(a.y * w); u.us[2] = f2bf(a.z * w); u.us[3] = f2bf(a.w * w);
    u.us[4] = f2bf(b.x * w); u.us[5] = f2bf(b.y * w); u.us[6] = f2bf(b.z * w); u.us[7] = f2bf(b.w * w);
    ((uint4*)Xs)[tid] = u.v;
}

// ---------------- CSR fill ----------------
__global__ void fill_kernel(const int* __restrict__ src, const int* __restrict__ dst,
                            int* __restrict__ cursor, int* __restrict__ csr) {
    int e = blockIdx.x * blockDim.x + threadIdx.x;
    if (e < N_EDGES) {
        int p = atomicAdd(&cursor[dst[e]], 1);
        csr[p] = src[e];
    }
}

// ---------------- fused gather + dual MFMA GEMM + relu/residual + BN stats ----------------
// 512 threads = 8 waves. Wave w: row-tile p=w&3 (16 rows), edge-half h=w>>2.
// Phase 1: each wave sums its edge-half of Xs rows -> bf16 partial in LDS[w].
// Phase 2: combine partials (+ *nd) -> A1 frags; A2 frags from f32 X.
// Phase 3: MFMA; wave handles coltiles [4h, 4h+4). Epilogue: relu+residual, BN partial sums.
__global__ __launch_bounds__(512) void fused_kernel(
    const float* __restrict__ X, const unsigned short* __restrict__ Xs,
    const int* __restrict__ csr, const int* __restrict__ row_start,
    const float* __restrict__ nd,
    const unsigned short* __restrict__ Wpk, const unsigned short* __restrict__ Wrpk,
    float* __restrict__ out, float* __restrict__ sums, float* __restrict__ sumsq) {
    __shared__ unsigned short P[8][16 * 136];  // 34.8KB; 272B row stride
    __shared__ float lsum[128];
    __shared__ float lsq[128];
    int t = threadIdx.x;
    int w = t >> 6;
    int l = t & 63;
    int p = w & 3;
    int h = w >> 2;
    if (t < 128) { lsum[t] = 0.f; lsq[t] = 0.f; }
    int rt = blockIdx.x * 4 + p;

    // ---- gather phase: bf16 partial sums of pre-scaled Xs rows ----
    for (int r = 0; r < 16; ++r) {
        int node = rt * 16 + r;
        float ax = 0.f, ay = 0.f;
        if (node < N_NODES) {
            int beg = row_start[node];
            int end = row_start[node + 1];
            int mid = beg + ((end - beg) >> 1);
            int e0 = h ? mid : beg;
            int e1 = h ? end : mid;
            int e = e0;
            for (; e + 3 < e1; e += 4) {
                int s0 = csr[e], s1 = csr[e + 1], s2 = csr[e + 2], s3 = csr[e + 3];
                unsigned u0 = *(const unsigned*)(Xs + (size_t)s0 * 128 + l * 2);
                unsigned u1 = *(const unsigned*)(Xs + (size_t)s1 * 128 + l * 2);
                unsigned u2 = *(const unsigned*)(Xs + (size_t)s2 * 128 + l * 2);
                unsigned u3 = *(const unsigned*)(Xs + (size_t)s3 * 128 + l * 2);
                ax += __uint_as_float(u0 << 16) + __uint_as_float(u1 << 16) +
                      __uint_as_float(u2 << 16) + __uint_as_float(u3 << 16);
                ay += __uint_as_float(u0 & 0xFFFF0000u) + __uint_as_float(u1 & 0xFFFF0000u) +
                      __uint_as_float(u2 & 0xFFFF0000u) + __uint_as_float(u3 & 0xFFFF0000u);
            }
            for (; e < e1; ++e) {
                unsigned u0 = *(const unsigned*)(Xs + (size_t)csr[e] * 128 + l * 2);
                ax += __uint_as_float(u0 << 16);
                ay += __uint_as_float(u0 & 0xFFFF0000u);
            }
        }
        ushort2 o;
        o.x = f2bf(ax);
        o.y = f2bf(ay);
        *(ushort2*)(&P[w][r * 136 + l * 2]) = o;
    }
    __syncthreads();

    // ---- combine partials -> A1 frags; A2 frags from f32 X ----
    int kg = l >> 4;
    int lr = l & 15;
    int arow = rt * 16 + lr;
    float ndv = (arow < N_NODES) ? nd[arow] : 0.f;
    int srow = arow < N_NODES ? arow : N_NODES - 1;
    bf16x8 a1[4], a2[4];
    #pragma unroll
    for (int kt = 0; kt < 4; ++kt) {
        const unsigned short* q0 = &P[p][lr * 136 + kt * 32 + kg * 8];
        const unsigned short* q1 = &P[p + 4][lr * 136 + kt * 32 + kg * 8];
        union { unsigned short us[8]; uint4 v; bf16x8 b; } v0, v1, o1, o2;
        v0.v = *(const uint4*)q0;
        v1.v = *(const uint4*)q1;
        #pragma unroll
        for (int j = 0; j < 8; ++j)
            o1.us[j] = f2bf((bf2f(v0.us[j]) + bf2f(v1.us[j])) * ndv);
        a1[kt] = o1.b;
        float4 xa = *(const float4*)(X + (size_t)srow * 128 + kt * 32 + kg * 8);
        float4 xb = *(const float4*)(X + (size_t)srow * 128 + kt * 32 + kg * 8 + 4);
        o2.us[0] = f2bf(xa.x); o2.us[1] = f2bf(xa.y); o2.us[2] = f2bf(xa.z); o2.us[3] = f2bf(xa.w);
        o2.us[4] = f2bf(xb.x); o2.us[5] = f2bf(xb.y); o2.us[6] = f2bf(xb.z); o2.us[7] = f2bf(xb.w);
        a2[kt] = o2.b;
    }
    const bf16x8* BW = (const bf16x8*)Wpk;
    const bf16x8* BR = (const bf16x8*)Wrpk;

    // ---- MFMA + epilogue: this wave's 4 coltiles ----
    #pragma unroll
    for (int ci = 0; ci < 4; ++ci) {
        int c = h * 4 + ci;
        f32x4 acc1 = {0.f, 0.f, 0.f, 0.f};
        f32x4 acc2 = {0.f, 0.f, 0.f, 0.f};
        #pragma unroll
        for (int kt = 0; kt < 4; ++kt)
            acc1 = __builtin_amdgcn_mfma_f32_16x16x32_bf16(a1[kt], BW[(c * 4 + kt) * 64 + l], acc1, 0, 0, 0);
        #pragma unroll
        for (int kt = 0; kt < 4; ++kt)
            acc2 = __builtin_amdgcn_mfma_f32_16x16x32_bf16(a2[kt], BR[(c * 4 + kt) * 64 + l], acc2, 0, 0, 0);
        int col = c * 16 + lr;
        float s = 0.f, s2 = 0.f;
        #pragma unroll
        for (int i = 0; i < 4; ++i) {
            int crow = rt * 16 + kg * 4 + i;  // C/D: col=lane&15, row=(lane>>4)*4+i
            if (crow < N_NODES) {
                float v = fmaxf(acc1[i], 0.f) + fmaxf(acc2[i], 0.f);
                out[(size_t)crow * 128 + col] = v;
                s += v;
                s2 += v * v;
            }
        }
        s += __shfl_xor(s, 16);
        s2 += __shfl_xor(s2, 16);
        s += __shfl_xor(s, 32);
        s2 += __shfl_xor(s2, 32);
        if (l < 16) {
            atomicAdd(&lsum[col], s);
            atomicAdd(&lsq[col], s2);
        }
    }
    __syncthreads();
    if (t < 128) {
        atomicAdd(&sums[t], lsum[t]);
        atomicAdd(&sumsq[t], lsq[t]);
    }
}

// ---------------- BatchNorm apply (in place, float4) ----------------
__global__ void bn_apply_kernel(float* __restrict__ out, const float* __restrict__ sums,
                                const float* __restrict__ sumsq, const float* __restrict__ gamma,
                                const float* __restrict__ beta) {
    int tid = blockIdx.x * 256 + threadIdx.x;
    if (tid >= N_NODES * D / 4) return;
    int d0 = (tid * 4) & 127;
    const float invN = 1.0f / (float)N_NODES;
    float4 v = ((float4*)out)[tid];
    float m0 = sums[d0] * invN, m1 = sums[d0 + 1] * invN, m2 = sums[d0 + 2] * invN, m3 = sums[d0 + 3] * invN;
    float i0 = rsqrtf(sumsq[d0] * invN - m0 * m0 + BN_EPS);
    float i1 = rsqrtf(sumsq[d0 + 1] * invN - m1 * m1 + BN_EPS);
    float i2 = rsqrtf(sumsq[d0 + 2] * invN - m2 * m2 + BN_EPS);
    float i3 = rsqrtf(sumsq[d0 + 3] * invN - m3 * m3 + BN_EPS);
    v.x = gamma[d0] * (v.x - m0) * i0 + beta[d0];
    v.y = gamma[d0 + 1] * (v.y - m1) * i1 + beta[d0 + 1];
    v.z = gamma[d0 + 2] * (v.z - m2) * i2 + beta[d0 + 2];
    v.w = gamma[d0 + 3] * (v.w - m3) * i3 + beta[d0 + 3];
    ((float4*)out)[tid] = v;
}

extern "C" void kernel_launch(void* const* d_in, const int* in_sizes, int n_in,
                              void* d_out, int out_size, void* d_ws, size_t ws_size,
                              hipStream_t stream) {
    const float* X = (const float*)d_in[0];
    const float* W = (const float*)d_in[1];
    const float* Wres = (const float*)d_in[2];
    const float* gamma = (const float*)d_in[3];
    const float* beta = (const float*)d_in[4];
    const int* src = (const int*)d_in[5];
    const int* dst = (const int*)d_in[6];
    float* out = (float*)d_out;

    int* wsI = (int*)d_ws;
    int* cnt_out = wsI + OFF_CNT_OUT;
    int* cnt_in = wsI + OFF_CNT_IN;
    float* sums = (float*)(wsI + OFF_SUMS);
    float* sumsq = (float*)(wsI + OFF_SUMSQ);
    int* part = wsI + OFF_PART;
    int* part2 = wsI + OFF_PART2;
    float* ns = (float*)(wsI + OFF_NS);
    float* nd = (float*)(wsI + OFF_ND);
    int* row_start = wsI + OFF_ROWSTART;
    int* cursor = wsI + OFF_CURSOR;
    int* csr = wsI + OFF_CSR;
    unsigned short* Wpk = (unsigned short*)(wsI + OFF_WPK);
    unsigned short* Wrpk = (unsigned short*)(wsI + OFF_WRPK);
    unsigned short* Xs = (unsigned short*)(wsI + OFF_XS);

    hipMemsetAsync(d_ws, 0, (size_t)ZERO_WORDS * 4, stream);

    deg_pack_kernel<<<(N_EDGES + 255) / 256, 256, 0, stream>>>(src, dst, cnt_out, cnt_in,
                                                               W, Wres, Wpk, Wrpk);
    norm_scanA_kernel<<<NBLK_SCAN, 256, 0, stream>>>(cnt_out, cnt_in, ns, nd, part);
    scanB_kernel<<<1, 256, 0, stream>>>(part, part2);
    scanC_kernel<<<NBLK_SCAN, 256, 0, stream>>>(cnt_in, part2, row_start, cursor);
    cvtXs_kernel<<<(N_NODES * D / 8 + 255) / 256, 256, 0, stream>>>(X, ns, Xs);
    fill_kernel<<<(N_EDGES + 255) / 256, 256, 0, stream>>>(src, dst, cursor, csr);
    fused_kernel<<<(N_NODES + 63) / 64, 512, 0, stream>>>(X, Xs, csr, row_start, nd,
                                                          Wpk, Wrpk, out, sums, sumsq);
    bn_apply_kernel<<<(N_NODES * D / 4 + 255) / 256, 256, 0, stream>>>(out, sums, sumsq, gamma, beta);
}

// Round 7
// 175.570 us; speedup vs baseline: 4.1417x; 1.1802x over previous
//
#include <hip/hip_runtime.h>

#define N_NODES 50000
#define N_EDGES 600000
#define D 128
#define BN_EPS 1e-5f
#define NBLK_SCAN 196   // ceil(50000/256)

// ws layout in 4-byte words:
#define OFF_CNT_OUT   0            // int[50048]
#define OFF_CNT_IN    50048        // int[50048]
#define OFF_SUMS8     100096       // float[8*128]
#define OFF_SUMSQ8    101120       // float[8*128]
#define ZERO_WORDS    102144       // memset range each call
#define OFF_PART      102144       // int[256] (fully overwritten)
#define OFF_PART2     102400       // int[256]
#define OFF_ND        102656       // float[50048]
#define OFF_ROWSTART  152704       // int[50052]
#define OFF_CURSOR    202756       // int[50048]
#define OFF_CSR       252804       // int[600000]
#define OFF_WPK       852804       // bf16[128*128] packed B-frags (16B aligned)
#define OFF_WRPK      860996       // bf16[128*128]
#define OFF_XS        869188       // bf16[50000*128] = X * norm_src (16B aligned)
// total = 4,069,188 words = 16.28 MB (<= 16.47 MB proven in R4/R6)

typedef __attribute__((ext_vector_type(8))) __bf16 bf16x8;
typedef __attribute__((ext_vector_type(4))) float f32x4;

static __device__ __forceinline__ unsigned short f2bf(float f) {
    unsigned u = __float_as_uint(f);
    unsigned r = (u + 0x7FFFu + ((u >> 16) & 1u)) >> 16;
    return (unsigned short)r;
}
static __device__ __forceinline__ float bf2f(unsigned short h) {
    return __uint_as_float(((unsigned)h) << 16);
}

// ---------------- degrees + fused W packing ----------------
// packW: frag (c=coltile 0..7, t=ktile 0..3): lane l holds B[t*32+(l>>4)*8+j][c*16+(l&15)]
__global__ void deg_pack_kernel(const int* __restrict__ src, const int* __restrict__ dst,
                                int* __restrict__ cnt_out, int* __restrict__ cnt_in,
                                const float* __restrict__ W, const float* __restrict__ Wres,
                                unsigned short* __restrict__ Wpk, unsigned short* __restrict__ Wrpk) {
    int i = blockIdx.x * 256 + threadIdx.x;
    if (i < 2048) {
        int l = i & 63;
        int t = (i >> 6) & 3;
        int c = i >> 8;
        int col = c * 16 + (l & 15);
        int k0 = t * 32 + (l >> 4) * 8;
        union { unsigned short us[8]; uint4 v; } u1, u2;
        #pragma unroll
        for (int j = 0; j < 8; ++j) {
            u1.us[j] = f2bf(W[(size_t)(k0 + j) * 128 + col]);
            u2.us[j] = f2bf(Wres[(size_t)(k0 + j) * 128 + col]);
        }
        ((uint4*)Wpk)[i] = u1.v;
        ((uint4*)Wrpk)[i] = u2.v;
    }
    if (i < N_EDGES) {
        atomicAdd(&cnt_out[src[i]], 1);
        atomicAdd(&cnt_in[dst[i]], 1);
    }
}

// ---------------- norms + scan level A + Xs conversion (fused) ----------------
__global__ void scanA_cvt_kernel(const int* __restrict__ cnt_out, const int* __restrict__ cnt_in,
                                 float* __restrict__ nd, int* __restrict__ part,
                                 const float* __restrict__ X, unsigned short* __restrict__ Xs) {
    __shared__ float lns[256];
    __shared__ int wsum[4];
    int i = blockIdx.x * 256 + threadIdx.x;
    int v = 0;
    float nsv = 0.f;
    if (i < N_NODES) {
        int co = cnt_out[i];
        int ci = cnt_in[i];
        nsv = rsqrtf((float)max(co, 1));
        nd[i] = rsqrtf((float)max(ci, 1));
        v = ci;
    }
    lns[threadIdx.x] = nsv;
    int lane = threadIdx.x & 63;
    int wid = threadIdx.x >> 6;
    int s = v;
    #pragma unroll
    for (int off = 32; off >= 1; off >>= 1) s += __shfl_xor(s, off);
    if (lane == 0) wsum[wid] = s;
    __syncthreads();
    if (threadIdx.x == 0) part[blockIdx.x] = wsum[0] + wsum[1] + wsum[2] + wsum[3];
    // conversion: this block's 256 rows, 16 threads per row x 8 elems
    int rbase = blockIdx.x * 256;
    int sub = threadIdx.x & 15;
    #pragma unroll 4
    for (int j = 0; j < 16; ++j) {
        int ridx = j * 16 + (threadIdx.x >> 4);
        int row = rbase + ridx;
        if (row < N_NODES) {
            float wv = lns[ridx];
            const float4* xp = (const float4*)(X + (size_t)row * 128 + sub * 8);
            float4 a = xp[0];
            float4 b = xp[1];
            union { unsigned short us[8]; uint4 u; } o;
            o.us[0] = f2bf(a.x * wv); o.us[1] = f2bf(a.y * wv);
            o.us[2] = f2bf(a.z * wv); o.us[3] = f2bf(a.w * wv);
            o.us[4] = f2bf(b.x * wv); o.us[5] = f2bf(b.y * wv);
            o.us[6] = f2bf(b.z * wv); o.us[7] = f2bf(b.w * wv);
            *(uint4*)(Xs + (size_t)row * 128 + sub * 8) = o.u;
        }
    }
}

// ---------------- scan level B ----------------
__global__ void scanB_kernel(const int* __restrict__ part, int* __restrict__ part2) {
    int tid = threadIdx.x;
    int v = (tid < NBLK_SCAN) ? part[tid] : 0;
    int lane = tid & 63;
    int wid = tid >> 6;
    int s = v;
    #pragma unroll
    for (int off = 1; off < 64; off <<= 1) {
        int u = __shfl_up(s, off);
        if (lane >= off) s += u;
    }
    __shared__ int wsum[4];
    if (lane == 63) wsum[wid] = s;
    __syncthreads();
    int add = 0;
    for (int k = 0; k < wid; ++k) add += wsum[k];
    if (tid < NBLK_SCAN) part2[tid] = add + s - v;
}

// ---------------- scan level C -> row_start, cursor ----------------
__global__ void scanC_kernel(const int* __restrict__ cnt_in, const int* __restrict__ part2,
                             int* __restrict__ row_start, int* __restrict__ cursor) {
    int i = blockIdx.x * 256 + threadIdx.x;
    int v = (i < N_NODES) ? cnt_in[i] : 0;
    int lane = threadIdx.x & 63;
    int wid = threadIdx.x >> 6;
    int s = v;
    #pragma unroll
    for (int off = 1; off < 64; off <<= 1) {
        int u = __shfl_up(s, off);
        if (lane >= off) s += u;
    }
    __shared__ int wsum[4];
    if (lane == 63) wsum[wid] = s;
    __syncthreads();
    int add = part2[blockIdx.x];
    for (int k = 0; k < wid; ++k) add += wsum[k];
    if (i < N_NODES) {
        int rs = add + s - v;
        row_start[i] = rs;
        cursor[i] = rs;
    }
    if (i == N_NODES) row_start[N_NODES] = N_EDGES;
}

// ---------------- CSR fill ----------------
__global__ void fill_kernel(const int* __restrict__ src, const int* __restrict__ dst,
                            int* __restrict__ cursor, int* __restrict__ csr) {
    int e = blockIdx.x * blockDim.x + threadIdx.x;
    if (e < N_EDGES) {
        int p = atomicAdd(&cursor[dst[e]], 1);
        csr[p] = src[e];
    }
}

// ---------------- fused gather + dual MFMA GEMM + relu/residual + BN partials ----------------
// 256 threads = 4 waves. Block = one 16-row tile (grid 3125, 50000 = 3125*16 exactly).
// Wave w gathers rows w*4..w*4+3 fully (no splitting) -> bf16 row sums in LDS.
// MFMA: wave w does coltiles 2w, 2w+1. BN: per-block col sums -> 8-slot global atomics.
__global__ __launch_bounds__(256) void fused_kernel(
    const float* __restrict__ X, const unsigned short* __restrict__ Xs,
    const int* __restrict__ csr, const int* __restrict__ row_start,
    const float* __restrict__ nd,
    const unsigned short* __restrict__ Wpk, const unsigned short* __restrict__ Wrpk,
    float* __restrict__ out, float* __restrict__ sums8, float* __restrict__ sumsq8) {
    __shared__ unsigned short P[16 * 136];  // 4.25KB, 272B row stride
    __shared__ float lsum[128];
    __shared__ float lsq[128];
    int t = threadIdx.x;
    int w = t >> 6;
    int l = t & 63;
    int rt = blockIdx.x;

    // ---- gather: wave-owned rows, 4-deep unrolled edge loop ----
    for (int rr = 0; rr < 4; ++rr) {
        int node = rt * 16 + w * 4 + rr;
        int beg = __builtin_amdgcn_readfirstlane(row_start[node]);
        int end = __builtin_amdgcn_readfirstlane(row_start[node + 1]);
        float ax = 0.f, ay = 0.f;
        int e = beg;
        for (; e + 3 < end; e += 4) {
            int s0 = csr[e], s1 = csr[e + 1], s2 = csr[e + 2], s3 = csr[e + 3];
            unsigned u0 = *(const unsigned*)(Xs + (size_t)s0 * 128 + l * 2);
            unsigned u1 = *(const unsigned*)(Xs + (size_t)s1 * 128 + l * 2);
            unsigned u2 = *(const unsigned*)(Xs + (size_t)s2 * 128 + l * 2);
            unsigned u3 = *(const unsigned*)(Xs + (size_t)s3 * 128 + l * 2);
            ax += __uint_as_float(u0 << 16) + __uint_as_float(u1 << 16) +
                  __uint_as_float(u2 << 16) + __uint_as_float(u3 << 16);
            ay += __uint_as_float(u0 & 0xFFFF0000u) + __uint_as_float(u1 & 0xFFFF0000u) +
                  __uint_as_float(u2 & 0xFFFF0000u) + __uint_as_float(u3 & 0xFFFF0000u);
        }
        for (; e < end; ++e) {
            unsigned u0 = *(const unsigned*)(Xs + (size_t)csr[e] * 128 + l * 2);
            ax += __uint_as_float(u0 << 16);
            ay += __uint_as_float(u0 & 0xFFFF0000u);
        }
        ushort2 o;
        o.x = f2bf(ax);
        o.y = f2bf(ay);
        *(ushort2*)(&P[(w * 4 + rr) * 136 + l * 2]) = o;
    }
    __syncthreads();

    // ---- fragment loads: A1 from P (* nd), A2 from f32 X ----
    int kg = l >> 4;
    int lr = l & 15;
    int arow = rt * 16 + lr;           // always < 50000
    float ndv = nd[arow];
    bf16x8 a1[4], a2[4];
    #pragma unroll
    for (int kt = 0; kt < 4; ++kt) {
        union { unsigned short us[8]; uint4 v; bf16x8 b; } v0, o1, o2;
        v0.v = *(const uint4*)(&P[lr * 136 + kt * 32 + kg * 8]);
        #pragma unroll
        for (int j = 0; j < 8; ++j) o1.us[j] = f2bf(bf2f(v0.us[j]) * ndv);
        a1[kt] = o1.b;
        float4 xa = *(const float4*)(X + (size_t)arow * 128 + kt * 32 + kg * 8);
        float4 xb = *(const float4*)(X + (size_t)arow * 128 + kt * 32 + kg * 8 + 4);
        o2.us[0] = f2bf(xa.x); o2.us[1] = f2bf(xa.y); o2.us[2] = f2bf(xa.z); o2.us[3] = f2bf(xa.w);
        o2.us[4] = f2bf(xb.x); o2.us[5] = f2bf(xb.y); o2.us[6] = f2bf(xb.z); o2.us[7] = f2bf(xb.w);
        a2[kt] = o2.b;
    }
    const bf16x8* BW = (const bf16x8*)Wpk;
    const bf16x8* BR = (const bf16x8*)Wrpk;

    // ---- MFMA + epilogue: wave w handles coltiles 2w, 2w+1 (col partition -> plain stores) ----
    #pragma unroll
    for (int ci = 0; ci < 2; ++ci) {
        int c = w * 2 + ci;
        f32x4 acc1 = {0.f, 0.f, 0.f, 0.f};
        f32x4 acc2 = {0.f, 0.f, 0.f, 0.f};
        #pragma unroll
        for (int kt = 0; kt < 4; ++kt)
            acc1 = __builtin_amdgcn_mfma_f32_16x16x32_bf16(a1[kt], BW[(c * 4 + kt) * 64 + l], acc1, 0, 0, 0);
        #pragma unroll
        for (int kt = 0; kt < 4; ++kt)
            acc2 = __builtin_amdgcn_mfma_f32_16x16x32_bf16(a2[kt], BR[(c * 4 + kt) * 64 + l], acc2, 0, 0, 0);
        int col = c * 16 + lr;
        float s = 0.f, s2 = 0.f;
        #pragma unroll
        for (int i = 0; i < 4; ++i) {
            int crow = rt * 16 + kg * 4 + i;  // C/D: col=lane&15, row=(lane>>4)*4+i
            float v = fmaxf(acc1[i], 0.f) + fmaxf(acc2[i], 0.f);
            out[(size_t)crow * 128 + col] = v;
            s += v;
            s2 += v * v;
        }
        s += __shfl_xor(s, 16);
        s2 += __shfl_xor(s2, 16);
        s += __shfl_xor(s, 32);
        s2 += __shfl_xor(s2, 32);
        if (l < 16) {
            lsum[col] = s;   // each col written by exactly one wave/lane
            lsq[col] = s2;
        }
    }
    __syncthreads();
    if (t < 128) {
        int slot = (blockIdx.x & 7) * 128 + t;
        atomicAdd(&sums8[slot], lsum[t]);
        atomicAdd(&sumsq8[slot], lsq[t]);
    }
}

// ---------------- BatchNorm apply (8-slot reduce in LDS, in-place float4) ----------------
__global__ void bn_apply_kernel(float* __restrict__ out, const float* __restrict__ sums8,
                                const float* __restrict__ sumsq8, const float* __restrict__ gamma,
                                const float* __restrict__ beta) {
    __shared__ float lmean[128], linv[128], lg[128], lb[128];
    int t = threadIdx.x;
    if (t < 128) {
        float s = 0.f, s2 = 0.f;
        #pragma unroll
        for (int k = 0; k < 8; ++k) {
            s += sums8[k * 128 + t];
            s2 += sumsq8[k * 128 + t];
        }
        const float invN = 1.0f / (float)N_NODES;
        float m = s * invN;
        lmean[t] = m;
        linv[t] = rsqrtf(s2 * invN - m * m + BN_EPS);
        lg[t] = gamma[t];
        lb[t] = beta[t];
    }
    __syncthreads();
    int tid = blockIdx.x * 256 + t;
    if (tid >= N_NODES * D / 4) return;
    int d0 = (tid * 4) & 127;
    float4 v = ((float4*)out)[tid];
    v.x = lg[d0] * (v.x - lmean[d0]) * linv[d0] + lb[d0];
    v.y = lg[d0 + 1] * (v.y - lmean[d0 + 1]) * linv[d0 + 1] + lb[d0 + 1];
    v.z = lg[d0 + 2] * (v.z - lmean[d0 + 2]) * linv[d0 + 2] + lb[d0 + 2];
    v.w = lg[d0 + 3] * (v.w - lmean[d0 + 3]) * linv[d0 + 3] + lb[d0 + 3];
    ((float4*)out)[tid] = v;
}

extern "C" void kernel_launch(void* const* d_in, const int* in_sizes, int n_in,
                              void* d_out, int out_size, void* d_ws, size_t ws_size,
                              hipStream_t stream) {
    const float* X = (const float*)d_in[0];
    const float* W = (const float*)d_in[1];
    const float* Wres = (const float*)d_in[2];
    const float* gamma = (const float*)d_in[3];
    const float* beta = (const float*)d_in[4];
    const int* src = (const int*)d_in[5];
    const int* dst = (const int*)d_in[6];
    float* out = (float*)d_out;

    int* wsI = (int*)d_ws;
    int* cnt_out = wsI + OFF_CNT_OUT;
    int* cnt_in = wsI + OFF_CNT_IN;
    float* sums8 = (float*)(wsI + OFF_SUMS8);
    float* sumsq8 = (float*)(wsI + OFF_SUMSQ8);
    int* part = wsI + OFF_PART;
    int* part2 = wsI + OFF_PART2;
    float* nd = (float*)(wsI + OFF_ND);
    int* row_start = wsI + OFF_ROWSTART;
    int* cursor = wsI + OFF_CURSOR;
    int* csr = wsI + OFF_CSR;
    unsigned short* Wpk = (unsigned short*)(wsI + OFF_WPK);
    unsigned short* Wrpk = (unsigned short*)(wsI + OFF_WRPK);
    unsigned short* Xs = (unsigned short*)(wsI + OFF_XS);

    hipMemsetAsync(d_ws, 0, (size_t)ZERO_WORDS * 4, stream);

    deg_pack_kernel<<<(N_EDGES + 255) / 256, 256, 0, stream>>>(src, dst, cnt_out, cnt_in,
                                                               W, Wres, Wpk, Wrpk);
    scanA_cvt_kernel<<<NBLK_SCAN, 256, 0, stream>>>(cnt_out, cnt_in, nd, part, X, Xs);
    scanB_kernel<<<1, 256, 0, stream>>>(part, part2);
    scanC_kernel<<<NBLK_SCAN, 256, 0, stream>>>(cnt_in, part2, row_start, cursor);
    fill_kernel<<<(N_EDGES + 255) / 256, 256, 0, stream>>>(src, dst, cursor, csr);
    fused_kernel<<<N_NODES / 16, 256, 0, stream>>>(X, Xs, csr, row_start, nd,
                                                   Wpk, Wrpk, out, sums8, sumsq8);
    bn_apply_kernel<<<(N_NODES * D / 4 + 255) / 256, 256, 0, stream>>>(out, sums8, sumsq8,
                                                                       gamma, beta);
}

// Round 8
// 170.078 us; speedup vs baseline: 4.2755x; 1.0323x over previous
//
#include <hip/hip_runtime.h>

#define N_NODES 50000
#define N_EDGES 600000
#define D 128
#define BN_EPS 1e-5f
#define NBLK_SCAN 196   // ceil(50000/256)

// ws layout in 4-byte words:
#define OFF_CNT_OUT   0            // int[50048]
#define OFF_CNT_IN    50048        // int[50048]
#define OFF_SUMS8     100096       // float[8*128]
#define OFF_SUMSQ8    101120       // float[8*128]
#define ZERO_WORDS    102144       // memset range each call
#define OFF_PART      102144       // int[256] (fully overwritten)
#define OFF_ND        102400       // float[50048]
#define OFF_ROWSTART  152448       // int[50052]
#define OFF_CURSOR    202500       // int[50048]
#define OFF_CSR       252548       // int[600000]
#define OFF_WPK       852548       // bf16[128*128] packed B-frags (16B aligned)
#define OFF_WRPK      860740       // bf16[128*128]
#define OFF_XS        868932       // bf16[50000*128] = X * norm_src (16B aligned)
// total = 4,068,932 words = 16.28 MB (< 16.47 MB proven in R4/R6)

typedef __attribute__((ext_vector_type(8))) __bf16 bf16x8;
typedef __attribute__((ext_vector_type(4))) float f32x4;

static __device__ __forceinline__ unsigned short f2bf(float f) {
    unsigned u = __float_as_uint(f);
    unsigned r = (u + 0x7FFFu + ((u >> 16) & 1u)) >> 16;
    return (unsigned short)r;
}
static __device__ __forceinline__ float bf2f(unsigned short h) {
    return __uint_as_float(((unsigned)h) << 16);
}

// ---------------- degrees (int2-vectorized) + fused W packing ----------------
// packW: frag (c=coltile 0..7, t=ktile 0..3): lane l holds B[t*32+(l>>4)*8+j][c*16+(l&15)]
__global__ void deg_pack_kernel(const int* __restrict__ src, const int* __restrict__ dst,
                                int* __restrict__ cnt_out, int* __restrict__ cnt_in,
                                const float* __restrict__ W, const float* __restrict__ Wres,
                                unsigned short* __restrict__ Wpk, unsigned short* __restrict__ Wrpk) {
    int i = blockIdx.x * 256 + threadIdx.x;
    if (i < 2048) {
        int l = i & 63;
        int t = (i >> 6) & 3;
        int c = i >> 8;
        int col = c * 16 + (l & 15);
        int k0 = t * 32 + (l >> 4) * 8;
        union { unsigned short us[8]; uint4 v; } u1, u2;
        #pragma unroll
        for (int j = 0; j < 8; ++j) {
            u1.us[j] = f2bf(W[(size_t)(k0 + j) * 128 + col]);
            u2.us[j] = f2bf(Wres[(size_t)(k0 + j) * 128 + col]);
        }
        ((uint4*)Wpk)[i] = u1.v;
        ((uint4*)Wrpk)[i] = u2.v;
    }
    if (i < N_EDGES / 2) {
        int2 s2 = ((const int2*)src)[i];
        int2 d2 = ((const int2*)dst)[i];
        atomicAdd(&cnt_out[s2.x], 1);
        atomicAdd(&cnt_out[s2.y], 1);
        atomicAdd(&cnt_in[d2.x], 1);
        atomicAdd(&cnt_in[d2.y], 1);
    }
}

// ---------------- norms + scan level A (block sums) + Xs conversion (fused) ----------------
__global__ void scanA_cvt_kernel(const int* __restrict__ cnt_out, const int* __restrict__ cnt_in,
                                 float* __restrict__ nd, int* __restrict__ part,
                                 const float* __restrict__ X, unsigned short* __restrict__ Xs) {
    __shared__ float lns[256];
    __shared__ int wsum[4];
    int i = blockIdx.x * 256 + threadIdx.x;
    int v = 0;
    float nsv = 0.f;
    if (i < N_NODES) {
        int co = cnt_out[i];
        int ci = cnt_in[i];
        nsv = rsqrtf((float)max(co, 1));
        nd[i] = rsqrtf((float)max(ci, 1));
        v = ci;
    }
    lns[threadIdx.x] = nsv;
    int lane = threadIdx.x & 63;
    int wid = threadIdx.x >> 6;
    int s = v;
    #pragma unroll
    for (int off = 32; off >= 1; off >>= 1) s += __shfl_xor(s, off);
    if (lane == 0) wsum[wid] = s;
    __syncthreads();
    if (threadIdx.x == 0) part[blockIdx.x] = wsum[0] + wsum[1] + wsum[2] + wsum[3];
    // conversion: this block's 256 rows, 16 threads per row x 8 elems
    int rbase = blockIdx.x * 256;
    int sub = threadIdx.x & 15;
    #pragma unroll 4
    for (int j = 0; j < 16; ++j) {
        int ridx = j * 16 + (threadIdx.x >> 4);
        int row = rbase + ridx;
        if (row < N_NODES) {
            float wv = lns[ridx];
            const float4* xp = (const float4*)(X + (size_t)row * 128 + sub * 8);
            float4 a = xp[0];
            float4 b = xp[1];
            union { unsigned short us[8]; uint4 u; } o;
            o.us[0] = f2bf(a.x * wv); o.us[1] = f2bf(a.y * wv);
            o.us[2] = f2bf(a.z * wv); o.us[3] = f2bf(a.w * wv);
            o.us[4] = f2bf(b.x * wv); o.us[5] = f2bf(b.y * wv);
            o.us[6] = f2bf(b.z * wv); o.us[7] = f2bf(b.w * wv);
            *(uint4*)(Xs + (size_t)row * 128 + sub * 8) = o.u;
        }
    }
}

// ---------------- scan C (fused B): prefix base via masked reduce, then local scan ----------------
__global__ void scanC_kernel(const int* __restrict__ cnt_in, const int* __restrict__ part,
                             int* __restrict__ row_start, int* __restrict__ cursor) {
    __shared__ int wsumB[4];
    __shared__ int wsum[4];
    int t = threadIdx.x;
    int lane = t & 63;
    int wid = t >> 6;
    // masked reduce of part[0..blockIdx.x-1]
    int pv = (t < NBLK_SCAN && t < (int)blockIdx.x) ? part[t] : 0;
    int sb = pv;
    #pragma unroll
    for (int off = 32; off >= 1; off >>= 1) sb += __shfl_xor(sb, off);
    if (lane == 0) wsumB[wid] = sb;
    // local exclusive scan of this block's cnt chunk
    int i = blockIdx.x * 256 + t;
    int v = (i < N_NODES) ? cnt_in[i] : 0;
    int s = v;
    #pragma unroll
    for (int off = 1; off < 64; off <<= 1) {
        int u = __shfl_up(s, off);
        if (lane >= off) s += u;
    }
    if (lane == 63) wsum[wid] = s;
    __syncthreads();
    int add = wsumB[0] + wsumB[1] + wsumB[2] + wsumB[3];
    for (int k = 0; k < wid; ++k) add += wsum[k];
    if (i < N_NODES) {
        int rs = add + s - v;
        row_start[i] = rs;
        cursor[i] = rs;
    }
    if (i == N_NODES) row_start[N_NODES] = N_EDGES;
}

// ---------------- CSR fill (int2-vectorized) ----------------
__global__ void fill_kernel(const int* __restrict__ src, const int* __restrict__ dst,
                            int* __restrict__ cursor, int* __restrict__ csr) {
    int i = blockIdx.x * blockDim.x + threadIdx.x;
    if (i < N_EDGES / 2) {
        int2 d2 = ((const int2*)dst)[i];
        int2 s2 = ((const int2*)src)[i];
        int p0 = atomicAdd(&cursor[d2.x], 1);
        csr[p0] = s2.x;
        int p1 = atomicAdd(&cursor[d2.y], 1);
        csr[p1] = s2.y;
    }
}

// ---------------- fused gather + dual MFMA GEMM + relu/residual + BN partials ----------------
// 256 threads = 4 waves, block = one 16-row tile (grid 3125).
// Gather: wave w owns rows w*4..w*4+3. Per row, each 16-lane group owns one edge;
// each lane loads 16B (8 bf16 cols). 8-edge unroll = 2 wide loads in flight.
// Cross-group combine via shfl_xor(16/32). MFMA: wave w does coltiles 2w, 2w+1.
__global__ __launch_bounds__(256) void fused_kernel(
    const float* __restrict__ X, const unsigned short* __restrict__ Xs,
    const int* __restrict__ csr, const int* __restrict__ row_start,
    const float* __restrict__ nd,
    const unsigned short* __restrict__ Wpk, const unsigned short* __restrict__ Wrpk,
    float* __restrict__ out, float* __restrict__ sums8, float* __restrict__ sumsq8) {
    __shared__ unsigned short P[16 * 136];  // 4.25KB, 272B row stride
    __shared__ float lsum[128];
    __shared__ float lsq[128];
    int t = threadIdx.x;
    int w = t >> 6;
    int l = t & 63;
    int sub = l & 15;   // col slice: cols sub*8 .. sub*8+7
    int grp = l >> 4;   // edge slot within a 4-edge group
    int rt = blockIdx.x;

    // ---- gather ----
    for (int rr = 0; rr < 4; ++rr) {
        int node = rt * 16 + w * 4 + rr;
        int beg = __builtin_amdgcn_readfirstlane(row_start[node]);
        int end = __builtin_amdgcn_readfirstlane(row_start[node + 1]);
        float acc[8];
        #pragma unroll
        for (int j = 0; j < 8; ++j) acc[j] = 0.f;
        int e = beg;
        for (; e + 7 < end; e += 8) {
            int sA = csr[e + grp];
            int sB = csr[e + 4 + grp];
            uint4 vA = *(const uint4*)(Xs + (size_t)sA * 128 + sub * 8);
            uint4 vB = *(const uint4*)(Xs + (size_t)sB * 128 + sub * 8);
            acc[0] += __uint_as_float(vA.x << 16);
            acc[1] += __uint_as_float(vA.x & 0xFFFF0000u);
            acc[2] += __uint_as_float(vA.y << 16);
            acc[3] += __uint_as_float(vA.y & 0xFFFF0000u);
            acc[4] += __uint_as_float(vA.z << 16);
            acc[5] += __uint_as_float(vA.z & 0xFFFF0000u);
            acc[6] += __uint_as_float(vA.w << 16);
            acc[7] += __uint_as_float(vA.w & 0xFFFF0000u);
            acc[0] += __uint_as_float(vB.x << 16);
            acc[1] += __uint_as_float(vB.x & 0xFFFF0000u);
            acc[2] += __uint_as_float(vB.y << 16);
            acc[3] += __uint_as_float(vB.y & 0xFFFF0000u);
            acc[4] += __uint_as_float(vB.z << 16);
            acc[5] += __uint_as_float(vB.z & 0xFFFF0000u);
            acc[6] += __uint_as_float(vB.w << 16);
            acc[7] += __uint_as_float(vB.w & 0xFFFF0000u);
        }
        for (; e < end; e += 4) {
            if (grp < end - e) {
                int sA = csr[e + grp];
                uint4 vA = *(const uint4*)(Xs + (size_t)sA * 128 + sub * 8);
                acc[0] += __uint_as_float(vA.x << 16);
                acc[1] += __uint_as_float(vA.x & 0xFFFF0000u);
                acc[2] += __uint_as_float(vA.y << 16);
                acc[3] += __uint_as_float(vA.y & 0xFFFF0000u);
                acc[4] += __uint_as_float(vA.z << 16);
                acc[5] += __uint_as_float(vA.z & 0xFFFF0000u);
                acc[6] += __uint_as_float(vA.w << 16);
                acc[7] += __uint_as_float(vA.w & 0xFFFF0000u);
            }
        }
        // combine the 4 edge-groups
        #pragma unroll
        for (int j = 0; j < 8; ++j) {
            acc[j] += __shfl_xor(acc[j], 16);
            acc[j] += __shfl_xor(acc[j], 32);
        }
        if (l < 16) {
            union { unsigned short us[8]; uint4 u; } o;
            #pragma unroll
            for (int j = 0; j < 8; ++j) o.us[j] = f2bf(acc[j]);
            *(uint4*)(&P[(w * 4 + rr) * 136 + sub * 8]) = o.u;
        }
    }
    __syncthreads();

    // ---- fragment loads: A1 from P (* nd), A2 from f32 X ----
    int kg = l >> 4;
    int lr = l & 15;
    int arow = rt * 16 + lr;           // always < 50000
    float ndv = nd[arow];
    bf16x8 a1[4], a2[4];
    #pragma unroll
    for (int kt = 0; kt < 4; ++kt) {
        union { unsigned short us[8]; uint4 v; bf16x8 b; } v0, o1, o2;
        v0.v = *(const uint4*)(&P[lr * 136 + kt * 32 + kg * 8]);
        #pragma unroll
        for (int j = 0; j < 8; ++j) o1.us[j] = f2bf(bf2f(v0.us[j]) * ndv);
        a1[kt] = o1.b;
        float4 xa = *(const float4*)(X + (size_t)arow * 128 + kt * 32 + kg * 8);
        float4 xb = *(const float4*)(X + (size_t)arow * 128 + kt * 32 + kg * 8 + 4);
        o2.us[0] = f2bf(xa.x); o2.us[1] = f2bf(xa.y); o2.us[2] = f2bf(xa.z); o2.us[3] = f2bf(xa.w);
        o2.us[4] = f2bf(xb.x); o2.us[5] = f2bf(xb.y); o2.us[6] = f2bf(xb.z); o2.us[7] = f2bf(xb.w);
        a2[kt] = o2.b;
    }
    const bf16x8* BW = (const bf16x8*)Wpk;
    const bf16x8* BR = (const bf16x8*)Wrpk;

    // ---- MFMA + epilogue: wave w handles coltiles 2w, 2w+1 (col partition -> plain stores) ----
    #pragma unroll
    for (int ci = 0; ci < 2; ++ci) {
        int c = w * 2 + ci;
        f32x4 acc1 = {0.f, 0.f, 0.f, 0.f};
        f32x4 acc2 = {0.f, 0.f, 0.f, 0.f};
        #pragma unroll
        for (int kt = 0; kt < 4; ++kt)
            acc1 = __builtin_amdgcn_mfma_f32_16x16x32_bf16(a1[kt], BW[(c * 4 + kt) * 64 + l], acc1, 0, 0, 0);
        #pragma unroll
        for (int kt = 0; kt < 4; ++kt)
            acc2 = __builtin_amdgcn_mfma_f32_16x16x32_bf16(a2[kt], BR[(c * 4 + kt) * 64 + l], acc2, 0, 0, 0);
        int col = c * 16 + lr;
        float s = 0.f, s2 = 0.f;
        #pragma unroll
        for (int i = 0; i < 4; ++i) {
            int crow = rt * 16 + kg * 4 + i;  // C/D: col=lane&15, row=(lane>>4)*4+i
            float v = fmaxf(acc1[i], 0.f) + fmaxf(acc2[i], 0.f);
            out[(size_t)crow * 128 + col] = v;
            s += v;
            s2 += v * v;
        }
        s += __shfl_xor(s, 16);
        s2 += __shfl_xor(s2, 16);
        s += __shfl_xor(s, 32);
        s2 += __shfl_xor(s2, 32);
        if (l < 16) {
            lsum[col] = s;   // each col written by exactly one wave/lane
            lsq[col] = s2;
        }
    }
    __syncthreads();
    if (t < 128) {
        int slot = (blockIdx.x & 7) * 128 + t;
        atomicAdd(&sums8[slot], lsum[t]);
        atomicAdd(&sumsq8[slot], lsq[t]);
    }
}

// ---------------- BatchNorm apply (8-slot reduce in LDS, in-place float4) ----------------
__global__ void bn_apply_kernel(float* __restrict__ out, const float* __restrict__ sums8,
                                const float* __restrict__ sumsq8, const float* __restrict__ gamma,
                                const float* __restrict__ beta) {
    __shared__ float lmean[128], linv[128], lg[128], lb[128];
    int t = threadIdx.x;
    if (t < 128) {
        float s = 0.f, s2 = 0.f;
        #pragma unroll
        for (int k = 0; k < 8; ++k) {
            s += sums8[k * 128 + t];
            s2 += sumsq8[k * 128 + t];
        }
        const float invN = 1.0f / (float)N_NODES;
        float m = s * invN;
        lmean[t] = m;
        linv[t] = rsqrtf(s2 * invN - m * m + BN_EPS);
        lg[t] = gamma[t];
        lb[t] = beta[t];
    }
    __syncthreads();
    int tid = blockIdx.x * 256 + t;
    if (tid >= N_NODES * D / 4) return;
    int d0 = (tid * 4) & 127;
    float4 v = ((float4*)out)[tid];
    v.x = lg[d0] * (v.x - lmean[d0]) * linv[d0] + lb[d0];
    v.y = lg[d0 + 1] * (v.y - lmean[d0 + 1]) * linv[d0 + 1] + lb[d0 + 1];
    v.z = lg[d0 + 2] * (v.z - lmean[d0 + 2]) * linv[d0 + 2] + lb[d0 + 2];
    v.w = lg[d0 + 3] * (v.w - lmean[d0 + 3]) * linv[d0 + 3] + lb[d0 + 3];
    ((float4*)out)[tid] = v;
}

extern "C" void kernel_launch(void* const* d_in, const int* in_sizes, int n_in,
                              void* d_out, int out_size, void* d_ws, size_t ws_size,
                              hipStream_t stream) {
    const float* X = (const float*)d_in[0];
    const float* W = (const float*)d_in[1];
    const float* Wres = (const float*)d_in[2];
    const float* gamma = (const float*)d_in[3];
    const float* beta = (const float*)d_in[4];
    const int* src = (const int*)d_in[5];
    const int* dst = (const int*)d_in[6];
    float* out = (float*)d_out;

    int* wsI = (int*)d_ws;
    int* cnt_out = wsI + OFF_CNT_OUT;
    int* cnt_in = wsI + OFF_CNT_IN;
    float* sums8 = (float*)(wsI + OFF_SUMS8);
    float* sumsq8 = (float*)(wsI + OFF_SUMSQ8);
    int* part = wsI + OFF_PART;
    float* nd = (float*)(wsI + OFF_ND);
    int* row_start = wsI + OFF_ROWSTART;
    int* cursor = wsI + OFF_CURSOR;
    int* csr = wsI + OFF_CSR;
    unsigned short* Wpk = (unsigned short*)(wsI + OFF_WPK);
    unsigned short* Wrpk = (unsigned short*)(wsI + OFF_WRPK);
    unsigned short* Xs = (unsigned short*)(wsI + OFF_XS);

    hipMemsetAsync(d_ws, 0, (size_t)ZERO_WORDS * 4, stream);

    deg_pack_kernel<<<(N_EDGES / 2 + 255) / 256, 256, 0, stream>>>(src, dst, cnt_out, cnt_in,
                                                                   W, Wres, Wpk, Wrpk);
    scanA_cvt_kernel<<<NBLK_SCAN, 256, 0, stream>>>(cnt_out, cnt_in, nd, part, X, Xs);
    scanC_kernel<<<NBLK_SCAN, 256, 0, stream>>>(cnt_in, part, row_start, cursor);
    fill_kernel<<<(N_EDGES / 2 + 255) / 256, 256, 0, stream>>>(src, dst, cursor, csr);
    fused_kernel<<<N_NODES / 16, 256, 0, stream>>>(X, Xs, csr, row_start, nd,
                                                   Wpk, Wrpk, out, sums8, sumsq8);
    bn_apply_kernel<<<(N_NODES * D / 4 + 255) / 256, 256, 0, stream>>>(out, sums8, sumsq8,
                                                                       gamma, beta);
}